// Round 3
// baseline (553.446 us; speedup 1.0000x reference)
//
#include <hip/hip_runtime.h>
#include <cstdint>
#include <cstddef>

typedef __bf16 bf16x8 __attribute__((ext_vector_type(8)));
typedef float  f32x16 __attribute__((ext_vector_type(16)));

__device__ __forceinline__ unsigned f2bf_u(float f){
  unsigned u = __float_as_uint(f);
  return (u + 0x7FFFu + ((u >> 16) & 1u)) >> 16;   // RNE
}
__device__ __forceinline__ unsigned short f2bf(float f){ return (unsigned short)f2bf_u(f); }
__device__ __forceinline__ unsigned pk2(float a, float b){ return f2bf_u(a) | (f2bf_u(b) << 16); }

// clamp-free tanh: 1 - 2/(e^{2x}+1); exp2 overflow/underflow saturate correctly.
__device__ __forceinline__ float fast_tanh(float x){
  float e = __builtin_amdgcn_exp2f(x * 2.8853900817779268f);  // e^{2x}
  return __builtin_fmaf(-2.0f, __builtin_amdgcn_rcpf(e + 1.0f), 1.0f);
}

#define MFMA(a,b,c) __builtin_amdgcn_mfma_f32_32x32x16_bf16((a),(b),(c),0,0,0)

__device__ __forceinline__ void ld_lds16(const void* g, void* l){
  __builtin_amdgcn_global_load_lds(
      (const __attribute__((address_space(1))) unsigned int*)g,
      (__attribute__((address_space(3))) unsigned int*)l, 16, 0, 0);
}

// ---------- prep: Wb fp32 -> bf16, frag-contiguous chunk order ----------
// 32 chunks of 16 KB, chunk t = gc*4+kq. Within chunk, slot16 u = ((ks*4+tj)*2+q)*32+col.
// slot data = Wb[k=tj][g=gc*32+col][K = kq*64 + ks*16 + q*8 .. +8]  (8 bf16 = 16 B)
__global__ void prep_wb(const float* __restrict__ Wb, unsigned short* __restrict__ dst){
  int s   = blockIdx.x*256 + threadIdx.x;   // 32768 slot16
  int u   = s & 1023;
  int t   = s >> 10;
  int col = u & 31;
  int q   = (u>>5) & 1;
  int tj  = (u>>6) & 3;
  int ks  = (u>>8) & 3;
  int kq  = t & 3;
  int gc  = t >> 2;
  const float* src = Wb + ((size_t)(tj*256 + gc*32 + col))*256 + kq*64 + ks*16 + q*8;
  float4 f0 = *reinterpret_cast<const float4*>(src);
  float4 f1 = *reinterpret_cast<const float4*>(src + 4);
  uint4 o = make_uint4(pk2(f0.x,f0.y), pk2(f0.z,f0.w), pk2(f1.x,f1.y), pk2(f1.z,f1.w));
  *reinterpret_cast<uint4*>(dst + (size_t)s*8) = o;
}

// ---------- prep: W1/W2 fp32 -> bf16, frag-major for direct global->reg B loads ----------
// per matrix: slot16 index = (ct*16+ks)*64 + lane; data = W[ct*32+(lane&31)][ks*16+(lane>>5)*8 ..+8]
__global__ void prep_w(const float* __restrict__ W1, const float* __restrict__ W2,
                       unsigned short* __restrict__ dst){
  int id = blockIdx.x*256 + threadIdx.x;     // 16384 slot16 (W1 then W2)
  const float* W = (id < 8192) ? W1 : W2;
  int s  = id & 8191;
  int l  = s & 63;
  int ks = (s>>6) & 15;
  int ct = (s>>10) & 7;
  const float* src = W + ((size_t)ct*32 + (l&31))*256 + ks*16 + (l>>5)*8;
  float4 f0 = *reinterpret_cast<const float4*>(src);
  float4 f1 = *reinterpret_cast<const float4*>(src + 4);
  uint4 o = make_uint4(pk2(f0.x,f0.y), pk2(f0.z,f0.w), pk2(f1.x,f1.y), pk2(f1.z,f1.w));
  *reinterpret_cast<uint4*>(dst + (size_t)id*8) = o;
}

// ---------- main fused kernel ----------
// block = 256 thr (4 waves), 32 n (=128 x-rows). A resident in registers (64 VGPR);
// Wb streamed via async global_load_lds dbuf, one ds_read_b128 per MFMA (imm offsets).
// nei (row-major, stride 264 => conflict-free b128 A reads) -> stages 2/3 with
// frag-major global B (no barriers in those K-loops).
__launch_bounds__(256, 3)
__global__ void tetra_main(const float* __restrict__ x,
                           const float* __restrict__ bb,
                           const float* __restrict__ b1,
                           const float* __restrict__ gam,
                           const float* __restrict__ bet,
                           const float* __restrict__ b2,
                           const unsigned short* __restrict__ wsWb,
                           const unsigned short* __restrict__ wsW1,
                           const unsigned short* __restrict__ wsW2,
                           float* __restrict__ out)
{
  constexpr int NSTR = 264;                      // dw stride 132 ≡ 4 (mod 32): b128-friendly
  __shared__ __align__(16) unsigned char smem[32768];        // 2 x 16 KB Wb chunks
  __shared__ __align__(16) unsigned short snei[32*NSTR + 8]; // nei / h buffer

  constexpr int PT[12][4] = {{0,1,2,3},{0,2,3,1},{0,3,1,2},{1,0,3,2},{1,2,0,3},{1,3,2,0},
                             {2,0,1,3},{2,1,3,0},{2,3,0,1},{3,0,2,1},{3,1,0,2},{3,2,1,0}};

  const int tid  = threadIdx.x;
  const int w    = tid >> 6;
  const int lane = tid & 63;
  const int l31  = lane & 31;
  const int q    = lane >> 5;

  // ---- A tile -> registers (bf16 packed). Lane: row l31 of wave slab, k-half q.
  uint4 fragA[16];
  {
    const float* arow = x + ((size_t)blockIdx.x*128 + (size_t)(w*32 + l31))*256 + q*8;
#pragma unroll
    for (int s = 0; s < 16; ++s){
      float4 f0 = *reinterpret_cast<const float4*>(arow + s*16);
      float4 f1 = *reinterpret_cast<const float4*>(arow + s*16 + 4);
      fragA[s] = make_uint4(pk2(f0.x,f0.y), pk2(f0.z,f0.w), pk2(f1.x,f1.y), pk2(f1.z,f1.w));
    }
  }

  // async stage of chunk t into parity half; wave w fills bytes [w*4096, w*4096+4096)
  auto stage = [&](int t){
    const char* g = (const char*)wsWb + ((size_t)t<<14) + (w<<12) + lane*16;
    char* lb = (char*)smem + ((t&1)<<14) + (w<<12);
#pragma unroll
    for (int i = 0; i < 4; ++i)
      ld_lds16(g + i*1024, lb + i*1024);
  };

  stage(0);

  // bias prefetch (gc=0)
  float bbn[4];
#pragma unroll
  for (int k = 0; k < 4; ++k) bbn[k] = bb[k*256 + l31];

  // ================= stage 1 =================
  int t = 0;
  for (int gc = 0; gc < 8; ++gc){
    float bbv[4];
#pragma unroll
    for (int k = 0; k < 4; ++k) bbv[k] = bbn[k];
    if (gc < 7){
#pragma unroll
      for (int k = 0; k < 4; ++k) bbn[k] = bb[k*256 + (gc+1)*32 + l31];
    }

    f32x16 acc[4];
#pragma unroll
    for (int k = 0; k < 4; ++k)
#pragma unroll
      for (int r = 0; r < 16; ++r) acc[k][r] = bbv[k];   // bias folded into C init

#pragma unroll
    for (int kq = 0; kq < 4; ++kq, ++t){
      __syncthreads();                       // chunk t ready; parity (t+1)&1 free
      if (t < 31) stage(t+1);
      const uint4* Bq = (const uint4*)(smem + ((t&1)<<14)) + q*32 + l31;
#pragma unroll
      for (int ks = 0; ks < 4; ++ks){
        bf16x8 av = __builtin_bit_cast(bf16x8, fragA[kq*4 + ks]);
#pragma unroll
        for (int tj = 0; tj < 4; ++tj){
          bf16x8 bv = __builtin_bit_cast(bf16x8, Bq[(ks*4 + tj)*64]);  // ds_read_b128, imm offset
          acc[tj] = MFMA(av, bv, acc[tj]);
        }
      }
    }

    // epilogue: tanh (bias already in), in-register 12-perm combine, nei/3 -> LDS
#pragma unroll
    for (int k = 0; k < 4; ++k)
#pragma unroll
      for (int r = 0; r < 16; ++r)
        acc[k][r] = fast_tanh(acc[k][r]);

    const int cb = gc*32 + l31;
#pragma unroll
    for (int nb = 0; nb < 4; ++nb){
      float s = 0.0f;
#pragma unroll
      for (int p = 0; p < 12; ++p){
        float v = acc[0][nb*4 + PT[p][0]] + acc[1][nb*4 + PT[p][1]]
                + acc[2][nb*4 + PT[p][2]] + acc[3][nb*4 + PT[p][3]];
        s += fmaxf(v, 0.0f);
      }
      snei[(w*8 + 2*nb + q)*NSTR + cb] = f2bf(s * (1.0f/3.0f));  // 2x64B rows: conflict-free
    }
  }

  __syncthreads();   // nei complete (cross-wave reads next)

  // ================= stage 2: z = (nei/3)@W1^T ; h = relu(z*inv*gamma+beta) =================
  const int ct0 = w*2, ct1 = w*2 + 1;
  f32x16 a2[2];
#pragma unroll
  for (int j = 0; j < 2; ++j)
#pragma unroll
    for (int r = 0; r < 16; ++r) a2[j][r] = 0.0f;
  {
    const uint4* W1f = (const uint4*)wsW1;
    uint4 bp[8][2];
#pragma unroll
    for (int i = 0; i < 8; ++i){
      bp[i][0] = W1f[(ct0*16 + i)*64 + lane];
      bp[i][1] = W1f[(ct1*16 + i)*64 + lane];
    }
#pragma unroll
    for (int ks = 0; ks < 16; ++ks){
      bf16x8 av = *reinterpret_cast<const bf16x8*>(&snei[l31*NSTR + ks*16 + q*8]); // b128
      uint4 c0 = bp[ks&7][0], c1 = bp[ks&7][1];
      if (ks < 8){
        bp[ks][0] = W1f[(ct0*16 + ks + 8)*64 + lane];
        bp[ks][1] = W1f[(ct1*16 + ks + 8)*64 + lane];
      }
      a2[0] = MFMA(av, __builtin_bit_cast(bf16x8, c0), a2[0]);
      a2[1] = MFMA(av, __builtin_bit_cast(bf16x8, c1), a2[1]);
    }
  }
  __syncthreads();   // all nei reads done before overwrite
  {
    const float inv = 0.9999950000374998f;   // 1/sqrt(1+1e-5)
#pragma unroll
    for (int tj = 0; tj < 2; ++tj){
      int col = (w*2 + tj)*32 + l31;
      float b1v = b1[col], gv = gam[col], btv = bet[col];
#pragma unroll
      for (int r = 0; r < 16; ++r){
        int row = (r&3) + 8*(r>>2) + 4*q;
        float z  = a2[tj][r] + b1v;
        snei[row*NSTR + col] = f2bf(fmaxf(z*inv*gv + btv, 0.0f));  // h overwrites nei
      }
    }
  }
  __syncthreads();   // h complete

  // ================= stage 3: out = h@W2^T + b2 =================
  f32x16 a3[2];
#pragma unroll
  for (int j = 0; j < 2; ++j)
#pragma unroll
    for (int r = 0; r < 16; ++r) a3[j][r] = 0.0f;
  {
    const uint4* W2f = (const uint4*)wsW2;
    uint4 bp[8][2];
#pragma unroll
    for (int i = 0; i < 8; ++i){
      bp[i][0] = W2f[(ct0*16 + i)*64 + lane];
      bp[i][1] = W2f[(ct1*16 + i)*64 + lane];
    }
#pragma unroll
    for (int ks = 0; ks < 16; ++ks){
      bf16x8 av = *reinterpret_cast<const bf16x8*>(&snei[l31*NSTR + ks*16 + q*8]);
      uint4 c0 = bp[ks&7][0], c1 = bp[ks&7][1];
      if (ks < 8){
        bp[ks][0] = W2f[(ct0*16 + ks + 8)*64 + lane];
        bp[ks][1] = W2f[(ct1*16 + ks + 8)*64 + lane];
      }
      a3[0] = MFMA(av, __builtin_bit_cast(bf16x8, c0), a3[0]);
      a3[1] = MFMA(av, __builtin_bit_cast(bf16x8, c1), a3[1]);
    }
  }
#pragma unroll
  for (int tj = 0; tj < 2; ++tj){
    int col = (w*2 + tj)*32 + l31;
    float b2v = b2[col];
#pragma unroll
    for (int r = 0; r < 16; ++r){
      int row = (r&3) + 8*(r>>2) + 4*q;
      out[((size_t)blockIdx.x*32 + row)*256 + col] = a3[tj][r] + b2v;
    }
  }
}

extern "C" void kernel_launch(void* const* d_in, const int* in_sizes, int n_in,
                              void* d_out, int out_size, void* d_ws, size_t ws_size,
                              hipStream_t stream)
{
  (void)n_in; (void)out_size; (void)ws_size;
  const float* x   = (const float*)d_in[0];
  const float* Wb  = (const float*)d_in[1];
  const float* bb  = (const float*)d_in[2];
  const float* W1  = (const float*)d_in[3];
  const float* b1  = (const float*)d_in[4];
  const float* gam = (const float*)d_in[5];
  const float* bet = (const float*)d_in[6];
  const float* W2  = (const float*)d_in[7];
  const float* b2  = (const float*)d_in[8];
  // d_in[9] = perms: fixed A4 rotation table, baked into the kernel.
  float* out = (float*)d_out;

  unsigned short* wsWb = (unsigned short*)d_ws;        // 512 KB
  unsigned short* wsW1 = wsWb + 262144;                // 128 KB
  unsigned short* wsW2 = wsW1 + 65536;                 // 128 KB  (768 KB total)

  prep_wb<<<dim3(128), dim3(256), 0, stream>>>(Wb, wsWb);
  prep_w <<<dim3(64),  dim3(256), 0, stream>>>(W1, W2, wsW1);

  const int N = in_sizes[0] / (4*256);   // 65536
  tetra_main<<<dim3(N/32), dim3(256), 0, stream>>>(x, bb, b1, gam, bet, b2,
                                                   wsWb, wsW1, wsW2, out);
}